// Round 4
// baseline (892.870 us; speedup 1.0000x reference)
//
#include <hip/hip_runtime.h>
#include <hip/hip_bf16.h>

typedef unsigned short u16;
typedef unsigned int   u32;

typedef __bf16 bf16x8 __attribute__((ext_vector_type(8)));
typedef float  f32x4  __attribute__((ext_vector_type(4)));

// ---------- helpers ----------
__device__ __forceinline__ u16 f2bf(float f) {  // RNE
  u32 u = __float_as_uint(f);
  u += 0x7fffu + ((u >> 16) & 1u);
  return (u16)(u >> 16);
}
__device__ __forceinline__ u32 pack2(float a, float b) {
  return (u32)f2bf(a) | ((u32)f2bf(b) << 16);
}

// Problem constants
#define TOK_M   78848   // B*N = 8*9856
#define DIM     256
#define NWIN    1024    // 8 * 8 * 16
#define WINL    77      // 7*11

// ---------- weight f32 -> bf16 conversion (all 4 matrices, one launch) ----------
__global__ __launch_bounds__(256)
void cvt_w(const float* __restrict__ w0, const float* __restrict__ w1,
           const float* __restrict__ w2, const float* __restrict__ w3,
           u16* __restrict__ out)
{
  const int i = (blockIdx.x * 256 + threadIdx.x) * 4;  // [0, 524288)
  const float* src; int off;
  if      (i < 196608) { src = w0; off = i; }
  else if (i < 262144) { src = w1; off = i - 196608; }
  else if (i < 393216) { src = w2; off = i - 262144; }
  else                 { src = w3; off = i - 393216; }
  float4 v = *(const float4*)(src + off);
  uint2 o; o.x = pack2(v.x, v.y); o.y = pack2(v.z, v.w);
  *(uint2*)(out + i) = o;
}

// ---------- LayerNorm (+ optional window-partition permutation), fp32 in, bf16 out ----------
template<bool PERM>
__global__ __launch_bounds__(256)
void ln_k(const float* __restrict__ X, const float* __restrict__ g,
          const float* __restrict__ bta, u16* __restrict__ Y)
{
  const int tid  = threadIdx.x;
  const int tok  = blockIdx.x * 4 + (tid >> 6);
  const int lane = tid & 63;
  float4 v = *(const float4*)(X + (size_t)tok * DIM + lane * 4);
  float s = v.x + v.y + v.z + v.w;
#pragma unroll
  for (int off = 32; off; off >>= 1) s += __shfl_xor(s, off);
  const float mu = s * (1.f / 256.f);
  const float dx = v.x - mu, dy = v.y - mu, dz = v.z - mu, dw = v.w - mu;
  float q = dx * dx + dy * dy + dz * dz + dw * dw;
#pragma unroll
  for (int off = 32; off; off >>= 1) q += __shfl_xor(q, off);
  const float rstd = rsqrtf(q * (1.f / 256.f) + 1e-5f);
  float4 gg = *(const float4*)(g + lane * 4);
  float4 bb = *(const float4*)(bta + lane * 4);
  const float y0 = dx * rstd * gg.x + bb.x;
  const float y1 = dy * rstd * gg.y + bb.y;
  const float y2 = dz * rstd * gg.z + bb.z;
  const float y3 = dw * rstd * gg.w + bb.w;
  size_t dest = (size_t)tok;
  if (PERM) {
    const int b  = tok / 9856, n = tok - b * 9856;
    const int y  = n / 176,  xc = n - y * 176;
    const int ih = y / 7,    rr = y - ih * 7;
    const int iw = xc / 11,  cc = xc - iw * 11;
    dest = (size_t)(((b * 8 + ih) * 16 + iw)) * 77 + rr * 11 + cc;
  }
  uint2 o;
  o.x = pack2(y0, y1);
  o.y = pack2(y2, y3);
  *(uint2*)(Y + dest * DIM + lane * 4) = o;
}

// ---------- Barrier-free direct-fragment MFMA GEMM ----------
// C[M, NT*128] = A(bf16)[M, KS*32] @ W(bf16)[NT*128, KS*32]^T + bias (+epi)
// One block = 128-row M-tile; 4 waves as 2x2 over 128x128; N-tiles looped
// INSIDE the block so A is read once. No LDS, no __syncthreads: A and B
// fragments load straight from global in MFMA layout (lane l16 = row,
// quad*8 = k-offset, 16B per lane). For KS==8 the wave's whole A operand
// is preloaded into 128 VGPRs; B is JIT-loaded per K-step (weights L2-hot).
// EPI: 0 none, 1 +res(f32), 2 exact GELU. OBF: 1 bf16 out, 0 f32 out.
template<int NT, int KS, int EPI, int OBF>
__global__ __launch_bounds__(256, 2)
void gemm_direct(const u16* __restrict__ A, const u16* __restrict__ W,
                 const float* __restrict__ bias, const float* __restrict__ res,
                 void* __restrict__ Cout)
{
  constexpr int K = KS * 32;
  constexpr int N = NT * 128;
  const int tid  = threadIdx.x;
  const int wave = tid >> 6, lane = tid & 63;
  const int wy = wave >> 1, wx = wave & 1;
  const int quad = lane >> 4, l16 = lane & 15;
  const int m0 = blockIdx.x * 128;

  const u16* Ap = A + (size_t)(m0 + wy * 64 + l16) * K + quad * 8;
  const u16* Wp = W + (size_t)(wx * 64 + l16) * K + quad * 8;

  // preloaded A fragments (KS==8 path): af[mi][ks]
  bf16x8 af[4][8];
  if constexpr (KS <= 8) {
#pragma unroll
    for (int mi = 0; mi < 4; ++mi)
#pragma unroll
      for (int ks = 0; ks < KS; ++ks)
        af[mi][ks] = *(const bf16x8*)(Ap + (size_t)mi * 16 * K + ks * 32);
  }

#pragma unroll
  for (int nt = 0; nt < NT; ++nt) {
    const u16* Wn = Wp + (size_t)nt * 128 * K;
    f32x4 acc[4][4];
#pragma unroll
    for (int i = 0; i < 4; ++i)
#pragma unroll
      for (int j = 0; j < 4; ++j) {
        f32x4 z = {0.f, 0.f, 0.f, 0.f};
        acc[i][j] = z;
      }

#pragma unroll
    for (int ks = 0; ks < KS; ++ks) {
      bf16x8 bv[4];
#pragma unroll
      for (int ni = 0; ni < 4; ++ni)
        bv[ni] = *(const bf16x8*)(Wn + (size_t)ni * 16 * K + ks * 32);
      bf16x8 av[4];
      if constexpr (KS <= 8) {
#pragma unroll
        for (int mi = 0; mi < 4; ++mi) av[mi] = af[mi][ks];
      } else {
#pragma unroll
        for (int mi = 0; mi < 4; ++mi)
          av[mi] = *(const bf16x8*)(Ap + (size_t)mi * 16 * K + ks * 32);
      }
#pragma unroll
      for (int mi = 0; mi < 4; ++mi)
#pragma unroll
        for (int ni = 0; ni < 4; ++ni)
          acc[mi][ni] = __builtin_amdgcn_mfma_f32_16x16x32_bf16(
              av[mi], bv[ni], acc[mi][ni], 0, 0, 0);
    }

    // epilogue: C/D layout col = l16 (+16*ni), row = quad*4 + e (+16*mi)
    const int gr0 = m0 + wy * 64 + quad * 4;
    const int gc0 = nt * 128 + wx * 64 + l16;
#pragma unroll
    for (int ni = 0; ni < 4; ++ni) {
      const int gc = gc0 + ni * 16;
      const float bvs = bias[gc];
#pragma unroll
      for (int mi = 0; mi < 4; ++mi) {
        const int gr = gr0 + mi * 16;
        f32x4 a = acc[mi][ni];
#pragma unroll
        for (int e = 0; e < 4; ++e) {
          float v = a[e] + bvs;
          const size_t idx = (size_t)(gr + e) * N + gc;
          if (EPI == 1) v += res[idx];
          else if (EPI == 2) v = 0.5f * v * (1.f + erff(v * 0.70710678118654752f));
          if (OBF) ((u16*)Cout)[idx] = f2bf(v);
          else     ((float*)Cout)[idx] = v;
        }
      }
    }
  }
}

// ---------- MFMA windowed attention: one WAVE per (window, head) ----------
#define PSTR 104
__global__ __launch_bounds__(128)
void attn_mfma(const u16* __restrict__ qkv, u16* __restrict__ onat)
{
  __shared__ __bf16 Pb[2][80 * PSTR];

  const int tid  = threadIdx.x;
  const int wave = tid >> 6, lane = tid & 63;
  const int quad = lane >> 4, l16 = lane & 15;
  const int pair = blockIdx.x * 2 + wave;     // [0, 8192)
  const int nw   = pair >> 3, head = pair & 7;
  const size_t base = (size_t)nw * 77 * 768;
  const int hoff = head * 32;
  __bf16* P = Pb[wave];

  {
    uint4 z = {0, 0, 0, 0};
    for (int r = lane; r < 80; r += 64) {
      *(uint4*)(P + r * PSTR + 80) = z;
      *(uint4*)(P + r * PSTR + 88) = z;
    }
  }

  bf16x8 qf[5], kf[5];
  const u16* qp = qkv + base + hoff + quad * 8;
#pragma unroll
  for (int mi = 0; mi < 5; ++mi) {
    const size_t row = (size_t)(l16 + 16 * mi) * 768;
    qf[mi] = *(const bf16x8*)(qp + row);
    kf[mi] = *(const bf16x8*)(qp + row + 256);
  }

  f32x4 s[5][5];
#pragma unroll
  for (int mi = 0; mi < 5; ++mi)
#pragma unroll
    for (int ni = 0; ni < 5; ++ni) {
      f32x4 z = {0.f, 0.f, 0.f, 0.f};
      s[mi][ni] = z;
    }
#pragma unroll
  for (int mi = 0; mi < 5; ++mi)
#pragma unroll
    for (int ni = 0; ni < 5; ++ni)
      s[mi][ni] = __builtin_amdgcn_mfma_f32_16x16x32_bf16(
          qf[mi], kf[ni], s[mi][ni], 0, 0, 0);

  bf16x8 vf[3][2];
  {
    const __bf16* vbb = (const __bf16*)(qkv + base + 512 + hoff + l16);
#pragma unroll
    for (int ks = 0; ks < 3; ++ks)
#pragma unroll
      for (int ni = 0; ni < 2; ++ni)
#pragma unroll
        for (int jj = 0; jj < 8; ++jj) {
          const int k = ks * 32 + quad * 8 + jj;
          vf[ks][ni][jj] = (k < 77) ? vbb[(size_t)k * 768 + 16 * ni] : (__bf16)0.f;
        }
  }

  if (l16 >= 13) {
#pragma unroll
    for (int mi = 0; mi < 5; ++mi)
#pragma unroll
      for (int e = 0; e < 4; ++e) s[mi][4][e] = -1e30f;
  }

  const float c = 0.17677669529663687f * 1.4426950408889634f;
  float inv[5][4];
#pragma unroll
  for (int mi = 0; mi < 5; ++mi)
#pragma unroll
    for (int e = 0; e < 4; ++e) {
      float mx = s[mi][0][e];
#pragma unroll
      for (int ni = 1; ni < 5; ++ni) mx = fmaxf(mx, s[mi][ni][e]);
#pragma unroll
      for (int off = 1; off < 16; off <<= 1) mx = fmaxf(mx, __shfl_xor(mx, off));
      float sum = 0.f;
#pragma unroll
      for (int ni = 0; ni < 5; ++ni) {
        const float ev = exp2f((s[mi][ni][e] - mx) * c);
        s[mi][ni][e] = ev;
        sum += ev;
      }
#pragma unroll
      for (int off = 1; off < 16; off <<= 1) sum += __shfl_xor(sum, off);
      inv[mi][e] = 1.f / sum;
    }

#pragma unroll
  for (int mi = 0; mi < 5; ++mi)
#pragma unroll
    for (int e = 0; e < 4; ++e) {
      const int m = quad * 4 + e + 16 * mi;
#pragma unroll
      for (int ni = 0; ni < 5; ++ni)
        P[m * PSTR + l16 + 16 * ni] = (__bf16)(s[mi][ni][e] * inv[mi][e]);
    }

  f32x4 o[5][2];
#pragma unroll
  for (int mi = 0; mi < 5; ++mi)
#pragma unroll
    for (int ni = 0; ni < 2; ++ni) {
      f32x4 z = {0.f, 0.f, 0.f, 0.f};
      o[mi][ni] = z;
    }
#pragma unroll
  for (int ks = 0; ks < 3; ++ks)
#pragma unroll
    for (int mi = 0; mi < 5; ++mi) {
      const bf16x8 afr = *(const bf16x8*)(P + (l16 + 16 * mi) * PSTR + ks * 32 + quad * 8);
#pragma unroll
      for (int ni = 0; ni < 2; ++ni)
        o[mi][ni] = __builtin_amdgcn_mfma_f32_16x16x32_bf16(
            afr, vf[ks][ni], o[mi][ni], 0, 0, 0);
    }

  const int b  = nw >> 7;
  const int ih = (nw >> 4) & 7;
  const int iw = nw & 15;
#pragma unroll
  for (int mi = 0; mi < 5; ++mi)
#pragma unroll
    for (int e = 0; e < 4; ++e) {
      const int t = quad * 4 + e + 16 * mi;
      if (t < 77) {
        const int rr = t / 11, cc = t - rr * 11;
        const int y = ih * 7 + rr, xc = iw * 11 + cc;
        const size_t nat = (size_t)b * 9856 + (size_t)y * 176 + xc;
        u16* dst = onat + nat * DIM + hoff + l16;
        dst[0]  = f2bf(o[mi][0][e]);
        dst[16] = f2bf(o[mi][1][e]);
      }
    }
}

// ---------- launcher ----------
extern "C" void kernel_launch(void* const* d_in, const int* in_sizes, int n_in,
                              void* d_out, int out_size, void* d_ws, size_t ws_size,
                              hipStream_t stream)
{
  (void)in_sizes; (void)n_in; (void)out_size; (void)ws_size;
  const float* x    = (const float*)d_in[0];
  const float* g1   = (const float*)d_in[1];
  const float* b1   = (const float*)d_in[2];
  const float* wqkv = (const float*)d_in[3];
  const float* bqkv = (const float*)d_in[4];
  const float* wout = (const float*)d_in[5];
  const float* bout = (const float*)d_in[6];
  const float* g2   = (const float*)d_in[7];
  const float* b2   = (const float*)d_in[8];
  const float* w1   = (const float*)d_in[9];
  const float* bf1  = (const float*)d_in[10];
  const float* w2   = (const float*)d_in[11];
  const float* bf2  = (const float*)d_in[12];

  char* ws = (char*)d_ws;
  u16*   qkv  = (u16*)(ws);                 // M*768*2 = 121110528  (reused: h = M*512*2)
  u16*   xn   = (u16*)(ws + 121110528);     // M*256*2 =  40370176  (reused: xn2)
  u16*   onat = (u16*)(ws + 161480704);     // M*256*2 =  40370176
  u16*   wb   = (u16*)(ws + 201850880);     // 524288*2 = 1048576
  u16*   wqkv_b = wb;
  u16*   wout_b = wb + 196608;
  u16*   w1_b   = wb + 262144;
  u16*   w2_b   = wb + 393216;
  float* x2   = (float*)d_out;              // x2 lives in d_out

  cvt_w<<<512, 256, 0, stream>>>(wqkv, wout, w1, w2, wb);
  ln_k<true><<<19712, 256, 0, stream>>>(x, g1, b1, xn);
  // qkv = xn @ Wqkv^T + b    (N=768, K=256)
  gemm_direct<6, 8, 0, 1><<<616, 256, 0, stream>>>(xn, wqkv_b, bqkv, nullptr, qkv);
  attn_mfma<<<4096, 128, 0, stream>>>(qkv, onat);
  // x2 = x + onat @ Wout^T + bout   (N=256, K=256, f32 into d_out)
  gemm_direct<2, 8, 1, 0><<<616, 256, 0, stream>>>(onat, wout_b, bout, x, x2);
  ln_k<false><<<19712, 256, 0, stream>>>(x2, g2, b2, xn);
  // h = gelu(xn @ W1^T + b1)  (N=512, K=256, bf16 in qkv region)
  gemm_direct<4, 8, 2, 1><<<616, 256, 0, stream>>>(xn, w1_b, bf1, nullptr, qkv);
  // out = x2 + h @ W2^T + b2  (N=256, K=512, in-place on d_out)
  gemm_direct<2, 16, 1, 0><<<616, 256, 0, stream>>>(qkv, w2_b, bf2, x2, x2);
}